// Round 6
// baseline (104.083 us; speedup 1.0000x reference)
//
#include <hip/hip_runtime.h>

#define BB 4
#define HH 480
#define WW 640

// cheap reciprocal of a double: f32 seed, ~1e-5 relative error.
// Valid where the use is scale-invariant or self-correcting (Newton).
__device__ __forceinline__ double crcp(double d) {
    return (double)__builtin_amdgcn_rcpf((float)d);
}

// ROUND 6 = MEASUREMENT PROBE: kernel body is byte-identical to the verified
// round-5 kernel; kernel_launch dispatches it TWICE (idempotent: pure function
// of input, rewrites identical outputs). dur_us_new - 84 = true kernel time K,
// which the top-5 fill flood has hidden for five rounds.
__global__ __launch_bounds__(256, 4) void d2n_kernel(const float* __restrict__ pts,
                                                     float* __restrict__ out) {
    int idx = blockIdx.x * 256 + threadIdx.x;
    if (idx >= BB * HH * WW) return;
    int x = idx % WW;
    int t1 = idx / WW;
    int y = t1 % HH;
    int b = t1 / HH;

    const size_t HW = (size_t)HH * WW;
    const float* xs = pts + ((size_t)b * 3 + 0) * HW;
    const float* ys = pts + ((size_t)b * 3 + 1) * HW;
    const float* zs = pts + ((size_t)b * 3 + 2) * HW;

    // ---- Branch-free stencil: clamped addresses, all 27 loads in flight ----
    int row[3], col[3];
    bool rin[3], cin[3];
#pragma unroll
    for (int k = 0; k < 3; ++k) {
        int yy = y + k - 1, xx = x + k - 1;
        rin[k] = (unsigned)yy < HH;
        cin[k] = (unsigned)xx < WW;
        row[k] = min(max(yy, 0), HH - 1) * WW;
        col[k] = min(max(xx, 0), WW - 1);
    }
    float px[9], py[9], pz[9];
    bool inb[9];
#pragma unroll
    for (int i = 0; i < 9; ++i) {
        int r = i / 3, c = i % 3;
        int o = row[r] + col[c];
        inb[i] = rin[r] & cin[c];
        pz[i] = zs[o];
        px[i] = xs[o];
        py[i] = ys[o];
    }

    // ---- Gram accumulation (f32, matches reference AtA precision) ----
    float sxx = 0.f, sxy = 0.f, sxz = 0.f, sx = 0.f;
    float syy = 0.f, syz = 0.f, sy = 0.f;
    float szz = 0.f, sz = 0.f, cnt = 0.f;
#pragma unroll
    for (int i = 0; i < 9; ++i) {
        float w = (inb[i] && pz[i] > 0.0f && pz[i] < 10.0f) ? 1.0f : 0.0f;
        float qx = px[i] * w, qy = py[i] * w, qz = pz[i] * w;
        sxx += qx * px[i]; sxy += qx * py[i]; sxz += qx * pz[i]; sx += qx;
        syy += qy * py[i]; syz += qy * pz[i]; sy += qy;
        szz += qz * pz[i]; sz += qz;
        cnt += w;
    }

    // ---- Promote to f64; scale by ~1/trace (uniform scale: eigvec-invariant) ----
    double tr = (double)sxx + (double)syy + (double)szz + (double)cnt;
    double it = crcp(tr);
    double m00 = sxx * it, m01 = sxy * it, m02 = sxz * it, m03 = sx * it;
    double m11 = syy * it, m12 = syz * it, m13 = sy * it;
    double m22 = szz * it, m23 = sz * it, m33 = cnt * it;

    // ---- Characteristic polynomial, STREAMED Laplace minor pairs (verified) ----
    double nA = m00 * m11 - m01 * m01;          // N01_01
    double nB = m22 * m33 - m23 * m23;          // N23_23
    double e4 = nA * nB;
    double P2 = m33 * nA, P3 = m22 * nA;
    double P0 = m11 * nB, P1 = m00 * nB;
    double e2 = nA + nB;

    nA = m00 * m12 - m02 * m01;                 // N01_02
    nB = m12 * m33 - m23 * m13;                 // N23_13
    e4 -= nA * nB;
    P3 -= m12 * nA;
    P0 -= m12 * nB;

    nA = m00 * m13 - m03 * m01;                 // N01_03
    nB = m12 * m23 - m22 * m13;                 // N23_12
    e4 += nA * nB;
    P2 -= m13 * nA;
    P0 += m13 * nB;

    nA = m01 * m12 - m02 * m11;                 // N01_12
    nB = m02 * m33 - m23 * m03;                 // N23_03
    e4 += nA * nB;
    P3 += m02 * nA;
    P1 -= m02 * nB;

    nA = m01 * m13 - m03 * m11;                 // N01_13
    nB = m02 * m23 - m22 * m03;                 // N23_02
    e4 -= nA * nB;
    P2 += m03 * nA;
    P1 += m03 * nB;

    nA = m02 * m13 - m03 * m12;                 // Ncross (N01_23 = N23_01)
    e4 += nA * nA;

    e2 += (m00 * m22 - m02 * m02) + (m00 * m33 - m03 * m03)
        + (m11 * m22 - m12 * m12) + (m11 * m33 - m13 * m13);
    double e1 = (m00 + m11) + (m22 + m33);
    double e3 = (P0 + P1) + (P2 + P3);

    // ---- Newton toward smallest eigenvalue: 8 f32 warm iters + 4 f64 polish.
    //      4 f64 iters is LOAD-BEARING (near-double-root pixels: rate-1/2
    //      linear regime; 2 iters -> 0.135, 3 -> 0.033, 4 passes). ----
    float e1f = (float)e1, e2f = (float)e2, e3f = (float)e3, e4f = (float)e4;
    float t31f = 3.0f * e1f, t22f = 2.0f * e2f;
    float lf = 0.0f;
#pragma unroll
    for (int itn = 0; itn < 8; ++itn) {
        float p  = (((lf - e1f) * lf + e2f) * lf - e3f) * lf + e4f;
        float dp = ((4.0f * lf - t31f) * lf + t22f) * lf - e3f;
        dp = fminf(dp, -1e-30f);
        lf = lf - p * __builtin_amdgcn_rcpf(dp);
        lf = fminf(fmaxf(lf, 0.0f), 0.26f);
    }
    double t31 = 3.0 * e1, t22 = 2.0 * e2;
    double lam = (double)lf;
#pragma unroll
    for (int itn = 0; itn < 4; ++itn) {
        double p  = (((lam - e1) * lam + e2) * lam - e3) * lam + e4;
        double dp = ((4.0 * lam - t31) * lam + t22) * lam - e3;
        dp = fmin(dp, -1e-30);
        lam = lam - p * crcp(dp);  // 1e-5-accurate step: self-correcting
        lam = fmin(fmax(lam, 0.0), 0.26);
    }

    // ---- Adjugate of B = M - lam I via shared Laplace 2x2 minors (f64) ----
    double d0 = m00 - lam, d1 = m11 - lam, d2 = m22 - lam, d3 = m33 - lam;
    double s0 = d0 * d1 - m01 * m01;
    double s1 = d0 * m12 - m01 * m02;
    double s2 = d0 * m13 - m01 * m03;
    double s3 = m01 * m12 - d1 * m02;
    double s4 = m01 * m13 - d1 * m03;
    double s5 = m02 * m13 - m12 * m03;   // = c0 by symmetry
    double c1 = m02 * m23 - m03 * d2;
    double c2 = m02 * d3 - m03 * m23;
    double c3 = m12 * m23 - m13 * d2;
    double c4 = m12 * d3 - m13 * m23;
    double c5 = d2 * d3 - m23 * m23;

    // ---- Convert entries once; selection + normalization in f32 ----
    float f00 = (float)( d1 * c5 - m12 * c4 + m13 * c3);
    float f01 = (float)(-m01 * c5 + m02 * c4 - m03 * c3);
    float f02 = (float)( m13 * s5 - m23 * s4 + d3 * s3);
    float f03 = (float)(-m12 * s5 + d2 * s4 - m23 * s3);
    float f11 = (float)( d0 * c5 - m02 * c2 + m03 * c1);
    float f12 = (float)(-m03 * s5 + m23 * s2 - d3 * s1);
    float f13 = (float)( m02 * s5 - d2 * s2 + m23 * s1);
    float f22 = (float)( m03 * s4 - m13 * s2 + d3 * s0);
    float f23 = (float)(-m02 * s4 + m12 * s2 - m23 * s0);
    float f33 = (float)( m02 * s3 - m12 * s1 + d2 * s0);

    // pick column with largest |diagonal| (= largest v1 comp^2; adj = c*v v^T)
    float bb = fabsf(f00);
    float fx = f00, fy = f01, fz = f02;
    float a1 = fabsf(f11);
    if (a1 > bb) { bb = a1; fx = f01; fy = f11; fz = f12; }
    float a2 = fabsf(f22);
    if (a2 > bb) { bb = a2; fx = f02; fy = f12; fz = f22; }
    float a3 = fabsf(f33);
    if (a3 > bb) { bb = a3; fx = f03; fy = f13; fz = f23; }

    float nd = fx * fx + fy * fy + fz * fz;
    float inv = __builtin_amdgcn_rsqf(fmaxf(nd, 1e-30f));
    float nx = fx * inv, ny = fy * inv, nz = fz * inv;

    int o = y * WW + x;
    float cx = px[4], cy = py[4], cz = pz[4];
    float dot = nx * cx + ny * cy + nz * cz;
    float sgn = (dot > 0.0f) ? 1.0f : ((dot < 0.0f) ? -1.0f : 0.0f);
    nx *= sgn; ny *= sgn; nz *= sgn;

    out[((size_t)b * 3 + 0) * HW + o] = nx;
    out[((size_t)b * 3 + 1) * HW + o] = ny;
    out[((size_t)b * 3 + 2) * HW + o] = nz;

    bool cvalid = (cz > 0.0f && cz < 10.0f);
    bool m = cvalid && (cnt >= 4.0f) && (nx * nx + ny * ny + nz * nz > 0.25f);
    out[(size_t)BB * 3 * HW + (size_t)b * HW + o] = m ? 1.0f : 0.0f;
}

extern "C" void kernel_launch(void* const* d_in, const int* in_sizes, int n_in,
                              void* d_out, int out_size, void* d_ws, size_t ws_size,
                              hipStream_t stream) {
    const float* pts = (const float*)d_in[0];
    float* out = (float*)d_out;
    int total = BB * HH * WW;
    // PROBE: dispatch twice. Idempotent -> identical outputs; the extra
    // dispatch's cost = the kernel's true duration K (dur_us_new - ~84).
    d2n_kernel<<<(total + 255) / 256, 256, 0, stream>>>(pts, out);
    d2n_kernel<<<(total + 255) / 256, 256, 0, stream>>>(pts, out);
}

// Round 7
// 85.204 us; speedup vs baseline: 1.2216x; 1.2216x over previous
//
#include <hip/hip_runtime.h>

#define BB 4
#define HH 480
#define WW 640
#define W2 (WW / 2)

// cheap reciprocal of a double: f32 seed, ~1e-5 relative error.
// Valid where the use is scale-invariant or self-correcting (Newton).
__device__ __forceinline__ double crcp(double d) {
    return (double)__builtin_amdgcn_rcpf((float)d);
}

// ROUND 7: ILP-2 — each thread computes TWO adjacent-x pixels with explicitly
// interleaved Newton chains. Per-pixel math is statement-identical to the
// verified round-5 kernel (probe measured K~20us at ~52% issue util: the gap
// is serial-chain latency, so pair two independent chains per thread).
// __launch_bounds__(256,2): give the allocator 256-VGPR headroom (est ~190).
__global__ __launch_bounds__(256, 2) void d2n_kernel(const float* __restrict__ pts,
                                                     float* __restrict__ out) {
    int idx = blockIdx.x * 256 + threadIdx.x;
    if (idx >= BB * HH * W2) return;
    int xp = idx % W2;
    int t1 = idx / W2;
    int y = t1 % HH;
    int b = t1 / HH;
    int x0 = xp * 2;

    const size_t HW = (size_t)HH * WW;
    const float* xs = pts + ((size_t)b * 3 + 0) * HW;
    const float* ys = pts + ((size_t)b * 3 + 1) * HW;
    const float* zs = pts + ((size_t)b * 3 + 2) * HW;

    // ---- Shared 3x4 stencil window for the pixel pair (clamped, branch-free) ----
    int row[3]; bool rin[3];
#pragma unroll
    for (int k = 0; k < 3; ++k) {
        int yy = y + k - 1;
        rin[k] = (unsigned)yy < HH;
        row[k] = min(max(yy, 0), HH - 1) * WW;
    }
    int col[4]; bool cin[4];
#pragma unroll
    for (int k = 0; k < 4; ++k) {
        int xx = x0 + k - 1;
        cin[k] = (unsigned)xx < WW;
        col[k] = min(max(xx, 0), WW - 1);
    }

    float pxv[12], pyv[12], pzv[12];
#pragma unroll
    for (int i = 0; i < 12; ++i) {
        int r = i >> 2, c = i & 3;
        int o = row[r] + col[c];
        pzv[i] = zs[o];
        pxv[i] = xs[o];
        pyv[i] = ys[o];
    }

    // ---- Gram accumulation per pixel (f32; same per-pixel op order as r5) ----
    float sxx[2], sxy[2], sxz[2], sxs[2], syy[2], syz[2], sys[2],
          szz[2], szs[2], cnt[2];
#pragma unroll
    for (int u = 0; u < 2; ++u) {
        float axx = 0.f, axy = 0.f, axz = 0.f, ax = 0.f;
        float ayy = 0.f, ayz = 0.f, ay = 0.f;
        float azz = 0.f, az = 0.f, ac = 0.f;
#pragma unroll
        for (int i = 0; i < 9; ++i) {
            int r = i / 3, c = i % 3;
            int j = r * 4 + c + u;
            bool ib = rin[r] & cin[c + u];
            float z = pzv[j];
            float w = (ib && z > 0.0f && z < 10.0f) ? 1.0f : 0.0f;
            float qx = pxv[j] * w, qy = pyv[j] * w, qz = z * w;
            axx += qx * pxv[j]; axy += qx * pyv[j]; axz += qx * z; ax += qx;
            ayy += qy * pyv[j]; ayz += qy * z; ay += qy;
            azz += qz * z; az += qz;
            ac += w;
        }
        sxx[u] = axx; sxy[u] = axy; sxz[u] = axz; sxs[u] = ax;
        syy[u] = ayy; syz[u] = ayz; sys[u] = ay;
        szz[u] = azz; szs[u] = az; cnt[u] = ac;
    }

    // ---- Promote to f64; streamed char-poly (verified r2/r4 formulas) ----
    double m00[2], m01[2], m02[2], m03[2], m11[2], m12[2], m13[2],
           m22[2], m23[2], m33[2];
    double e1[2], e2[2], e3[2], e4[2];
#pragma unroll
    for (int u = 0; u < 2; ++u) {
        double tr = (double)sxx[u] + (double)syy[u] + (double)szz[u] + (double)cnt[u];
        double it = crcp(tr);
        m00[u] = sxx[u] * it; m01[u] = sxy[u] * it; m02[u] = sxz[u] * it; m03[u] = sxs[u] * it;
        m11[u] = syy[u] * it; m12[u] = syz[u] * it; m13[u] = sys[u] * it;
        m22[u] = szz[u] * it; m23[u] = szs[u] * it; m33[u] = cnt[u] * it;

        double nA = m00[u] * m11[u] - m01[u] * m01[u];     // N01_01
        double nB = m22[u] * m33[u] - m23[u] * m23[u];     // N23_23
        double E4 = nA * nB;
        double P2 = m33[u] * nA, P3 = m22[u] * nA;
        double P0 = m11[u] * nB, P1 = m00[u] * nB;
        double E2 = nA + nB;

        nA = m00[u] * m12[u] - m02[u] * m01[u];            // N01_02
        nB = m12[u] * m33[u] - m23[u] * m13[u];            // N23_13
        E4 -= nA * nB; P3 -= m12[u] * nA; P0 -= m12[u] * nB;

        nA = m00[u] * m13[u] - m03[u] * m01[u];            // N01_03
        nB = m12[u] * m23[u] - m22[u] * m13[u];            // N23_12
        E4 += nA * nB; P2 -= m13[u] * nA; P0 += m13[u] * nB;

        nA = m01[u] * m12[u] - m02[u] * m11[u];            // N01_12
        nB = m02[u] * m33[u] - m23[u] * m03[u];            // N23_03
        E4 += nA * nB; P3 += m02[u] * nA; P1 -= m02[u] * nB;

        nA = m01[u] * m13[u] - m03[u] * m11[u];            // N01_13
        nB = m02[u] * m23[u] - m22[u] * m03[u];            // N23_02
        E4 -= nA * nB; P2 += m03[u] * nA; P1 += m03[u] * nB;

        nA = m02[u] * m13[u] - m03[u] * m12[u];            // Ncross
        E4 += nA * nA;

        E2 += (m00[u] * m22[u] - m02[u] * m02[u]) + (m00[u] * m33[u] - m03[u] * m03[u])
            + (m11[u] * m22[u] - m12[u] * m12[u]) + (m11[u] * m33[u] - m13[u] * m13[u]);
        e1[u] = (m00[u] + m11[u]) + (m22[u] + m33[u]);
        e2[u] = E2;
        e3[u] = (P0 + P1) + (P2 + P3);
        e4[u] = E4;
    }

    // ---- Newton, INTERLEAVED across the pixel pair: 8 f32 warm + 4 f64.
    //      4 f64 iters is LOAD-BEARING (near-double-root pixels: rate-1/2
    //      linear regime; 2 iters -> 0.135, 3 -> 0.033, 4 passes). ----
    float e1f[2], e2f[2], e3f[2], e4f[2], t31f[2], t22f[2], lf[2];
#pragma unroll
    for (int u = 0; u < 2; ++u) {
        e1f[u] = (float)e1[u]; e2f[u] = (float)e2[u];
        e3f[u] = (float)e3[u]; e4f[u] = (float)e4[u];
        t31f[u] = 3.0f * e1f[u]; t22f[u] = 2.0f * e2f[u];
        lf[u] = 0.0f;
    }
#pragma unroll
    for (int itn = 0; itn < 8; ++itn) {
#pragma unroll
        for (int u = 0; u < 2; ++u) {
            float p  = (((lf[u] - e1f[u]) * lf[u] + e2f[u]) * lf[u] - e3f[u]) * lf[u] + e4f[u];
            float dp = ((4.0f * lf[u] - t31f[u]) * lf[u] + t22f[u]) * lf[u] - e3f[u];
            dp = fminf(dp, -1e-30f);
            lf[u] = lf[u] - p * __builtin_amdgcn_rcpf(dp);
            lf[u] = fminf(fmaxf(lf[u], 0.0f), 0.26f);
        }
    }
    double lam[2], t31[2], t22[2];
#pragma unroll
    for (int u = 0; u < 2; ++u) {
        t31[u] = 3.0 * e1[u]; t22[u] = 2.0 * e2[u];
        lam[u] = (double)lf[u];
    }
#pragma unroll
    for (int itn = 0; itn < 4; ++itn) {
#pragma unroll
        for (int u = 0; u < 2; ++u) {
            double p  = (((lam[u] - e1[u]) * lam[u] + e2[u]) * lam[u] - e3[u]) * lam[u] + e4[u];
            double dp = ((4.0 * lam[u] - t31[u]) * lam[u] + t22[u]) * lam[u] - e3[u];
            dp = fmin(dp, -1e-30);
            lam[u] = lam[u] - p * crcp(dp);   // self-correcting step
            lam[u] = fmin(fmax(lam[u], 0.0), 0.26);
        }
    }

    // ---- Adjugate of B = M - lam I (f64 minors) + f32 selection tail ----
    float nxo[2], nyo[2], nzo[2], msk[2];
#pragma unroll
    for (int u = 0; u < 2; ++u) {
        double M00 = m00[u], M01 = m01[u], M02 = m02[u], M03 = m03[u];
        double M11 = m11[u], M12 = m12[u], M13 = m13[u];
        double M22 = m22[u], M23 = m23[u];
        double L = lam[u];
        double d0 = M00 - L, d1 = M11 - L, d2 = M22 - L, d3 = m33[u] - L;
        double s0 = d0 * d1 - M01 * M01;
        double s1 = d0 * M12 - M01 * M02;
        double s2 = d0 * M13 - M01 * M03;
        double s3 = M01 * M12 - d1 * M02;
        double s4 = M01 * M13 - d1 * M03;
        double s5 = M02 * M13 - M12 * M03;   // = c0 by symmetry
        double c1 = M02 * M23 - M03 * d2;
        double c2 = M02 * d3 - M03 * M23;
        double c3 = M12 * M23 - M13 * d2;
        double c4 = M12 * d3 - M13 * M23;
        double c5 = d2 * d3 - M23 * M23;

        float f00 = (float)( d1 * c5 - M12 * c4 + M13 * c3);
        float f01 = (float)(-M01 * c5 + M02 * c4 - M03 * c3);
        float f02 = (float)( M13 * s5 - M23 * s4 + d3 * s3);
        float f03 = (float)(-M12 * s5 + d2 * s4 - M23 * s3);
        float f11 = (float)( d0 * c5 - M02 * c2 + M03 * c1);
        float f12 = (float)(-M03 * s5 + M23 * s2 - d3 * s1);
        float f13 = (float)( M02 * s5 - d2 * s2 + M23 * s1);
        float f22 = (float)( M03 * s4 - M13 * s2 + d3 * s0);
        float f23 = (float)(-M02 * s4 + M12 * s2 - M23 * s0);
        float f33 = (float)( M02 * s3 - M12 * s1 + d2 * s0);

        // pick column with largest |diagonal| (adj = c*v v^T)
        float bb = fabsf(f00);
        float fx = f00, fy = f01, fz = f02;
        float a1 = fabsf(f11);
        if (a1 > bb) { bb = a1; fx = f01; fy = f11; fz = f12; }
        float a2 = fabsf(f22);
        if (a2 > bb) { bb = a2; fx = f02; fy = f12; fz = f22; }
        float a3 = fabsf(f33);
        if (a3 > bb) { bb = a3; fx = f03; fy = f13; fz = f23; }

        float nd = fx * fx + fy * fy + fz * fz;
        float inv = __builtin_amdgcn_rsqf(fmaxf(nd, 1e-30f));
        float nx = fx * inv, ny = fy * inv, nz = fz * inv;

        float cx = pxv[5 + u], cy = pyv[5 + u], cz = pzv[5 + u];
        float dot = nx * cx + ny * cy + nz * cz;
        float sgn = (dot > 0.0f) ? 1.0f : ((dot < 0.0f) ? -1.0f : 0.0f);
        nxo[u] = nx * sgn; nyo[u] = ny * sgn; nzo[u] = nz * sgn;

        bool cvalid = (cz > 0.0f && cz < 10.0f);
        bool m = cvalid && (cnt[u] >= 4.0f) &&
                 (nxo[u] * nxo[u] + nyo[u] * nyo[u] + nzo[u] * nzo[u] > 0.25f);
        msk[u] = m ? 1.0f : 0.0f;
    }

    // ---- Paired float2 stores (x0 even -> 8B aligned) ----
    int o = y * WW + x0;
    *reinterpret_cast<float2*>(&out[((size_t)b * 3 + 0) * HW + o]) = make_float2(nxo[0], nxo[1]);
    *reinterpret_cast<float2*>(&out[((size_t)b * 3 + 1) * HW + o]) = make_float2(nyo[0], nyo[1]);
    *reinterpret_cast<float2*>(&out[((size_t)b * 3 + 2) * HW + o]) = make_float2(nzo[0], nzo[1]);
    *reinterpret_cast<float2*>(&out[(size_t)BB * 3 * HW + (size_t)b * HW + o]) = make_float2(msk[0], msk[1]);
}

extern "C" void kernel_launch(void* const* d_in, const int* in_sizes, int n_in,
                              void* d_out, int out_size, void* d_ws, size_t ws_size,
                              hipStream_t stream) {
    const float* pts = (const float*)d_in[0];
    float* out = (float*)d_out;
    int total = BB * HH * W2;
    d2n_kernel<<<(total + 255) / 256, 256, 0, stream>>>(pts, out);
}

// Round 8
// 83.900 us; speedup vs baseline: 1.2406x; 1.0155x over previous
//
#include <hip/hip_runtime.h>

#define BB 4
#define HH 480
#define WW 640

// cheap reciprocal of a double: f32 seed, ~1e-5 relative error.
// Valid where the use is scale-invariant or self-correcting (Newton).
__device__ __forceinline__ double crcp(double d) {
    return (double)__builtin_amdgcn_rcpf((float)d);
}

// FINAL (reverted to verified round-5 config, single dispatch).
// Session findings baked into this kernel:
//  - 4 f64 Newton iters are LOAD-BEARING (2 iters -> absmax 0.135,
//    3 -> 0.033, 4 -> 0.0039 = bf16 floor): near-double-root pixels put
//    Newton in the rate-1/2 linear regime.
//  - f64 char-poly + f64 adjugate minors required (cancellation); the
//    selection/normalization tail is safely f32.
//  - dur_us is envelope-dominated: kernel K ~= 20.3 us (round-6 double
//    dispatch probe); ~64 us is harness re-poison fill + memset + launch.
//    Op-count cuts (-35% f64), occupancy cap (256,4), and ILP-2 all moved
//    dur_us < 1.5 us -> practical floor reached.
__global__ __launch_bounds__(256, 4) void d2n_kernel(const float* __restrict__ pts,
                                                     float* __restrict__ out) {
    int idx = blockIdx.x * 256 + threadIdx.x;
    if (idx >= BB * HH * WW) return;
    int x = idx % WW;
    int t1 = idx / WW;
    int y = t1 % HH;
    int b = t1 / HH;

    const size_t HW = (size_t)HH * WW;
    const float* xs = pts + ((size_t)b * 3 + 0) * HW;
    const float* ys = pts + ((size_t)b * 3 + 1) * HW;
    const float* zs = pts + ((size_t)b * 3 + 2) * HW;

    // ---- Branch-free stencil: clamped addresses, all 27 loads in flight ----
    int row[3], col[3];
    bool rin[3], cin[3];
#pragma unroll
    for (int k = 0; k < 3; ++k) {
        int yy = y + k - 1, xx = x + k - 1;
        rin[k] = (unsigned)yy < HH;
        cin[k] = (unsigned)xx < WW;
        row[k] = min(max(yy, 0), HH - 1) * WW;
        col[k] = min(max(xx, 0), WW - 1);
    }
    float px[9], py[9], pz[9];
    bool inb[9];
#pragma unroll
    for (int i = 0; i < 9; ++i) {
        int r = i / 3, c = i % 3;
        int o = row[r] + col[c];
        inb[i] = rin[r] & cin[c];
        pz[i] = zs[o];
        px[i] = xs[o];
        py[i] = ys[o];
    }

    // ---- Gram accumulation (f32, matches reference AtA precision) ----
    float sxx = 0.f, sxy = 0.f, sxz = 0.f, sx = 0.f;
    float syy = 0.f, syz = 0.f, sy = 0.f;
    float szz = 0.f, sz = 0.f, cnt = 0.f;
#pragma unroll
    for (int i = 0; i < 9; ++i) {
        float w = (inb[i] && pz[i] > 0.0f && pz[i] < 10.0f) ? 1.0f : 0.0f;
        float qx = px[i] * w, qy = py[i] * w, qz = pz[i] * w;
        sxx += qx * px[i]; sxy += qx * py[i]; sxz += qx * pz[i]; sx += qx;
        syy += qy * py[i]; syz += qy * pz[i]; sy += qy;
        szz += qz * pz[i]; sz += qz;
        cnt += w;
    }

    // ---- Promote to f64; scale by ~1/trace (uniform scale: eigvec-invariant) ----
    double tr = (double)sxx + (double)syy + (double)szz + (double)cnt;
    double it = crcp(tr);
    double m00 = sxx * it, m01 = sxy * it, m02 = sxz * it, m03 = sx * it;
    double m11 = syy * it, m12 = syz * it, m13 = sy * it;
    double m22 = szz * it, m23 = sz * it, m33 = cnt * it;

    // ---- Characteristic polynomial, STREAMED Laplace minor pairs (verified) ----
    double nA = m00 * m11 - m01 * m01;          // N01_01
    double nB = m22 * m33 - m23 * m23;          // N23_23
    double e4 = nA * nB;
    double P2 = m33 * nA, P3 = m22 * nA;
    double P0 = m11 * nB, P1 = m00 * nB;
    double e2 = nA + nB;

    nA = m00 * m12 - m02 * m01;                 // N01_02
    nB = m12 * m33 - m23 * m13;                 // N23_13
    e4 -= nA * nB;
    P3 -= m12 * nA;
    P0 -= m12 * nB;

    nA = m00 * m13 - m03 * m01;                 // N01_03
    nB = m12 * m23 - m22 * m13;                 // N23_12
    e4 += nA * nB;
    P2 -= m13 * nA;
    P0 += m13 * nB;

    nA = m01 * m12 - m02 * m11;                 // N01_12
    nB = m02 * m33 - m23 * m03;                 // N23_03
    e4 += nA * nB;
    P3 += m02 * nA;
    P1 -= m02 * nB;

    nA = m01 * m13 - m03 * m11;                 // N01_13
    nB = m02 * m23 - m22 * m03;                 // N23_02
    e4 -= nA * nB;
    P2 += m03 * nA;
    P1 += m03 * nB;

    nA = m02 * m13 - m03 * m12;                 // Ncross (N01_23 = N23_01)
    e4 += nA * nA;

    e2 += (m00 * m22 - m02 * m02) + (m00 * m33 - m03 * m03)
        + (m11 * m22 - m12 * m12) + (m11 * m33 - m13 * m13);
    double e1 = (m00 + m11) + (m22 + m33);
    double e3 = (P0 + P1) + (P2 + P3);

    // ---- Newton toward smallest eigenvalue: 8 f32 warm iters + 4 f64 polish ----
    float e1f = (float)e1, e2f = (float)e2, e3f = (float)e3, e4f = (float)e4;
    float t31f = 3.0f * e1f, t22f = 2.0f * e2f;
    float lf = 0.0f;
#pragma unroll
    for (int itn = 0; itn < 8; ++itn) {
        float p  = (((lf - e1f) * lf + e2f) * lf - e3f) * lf + e4f;
        float dp = ((4.0f * lf - t31f) * lf + t22f) * lf - e3f;
        dp = fminf(dp, -1e-30f);
        lf = lf - p * __builtin_amdgcn_rcpf(dp);
        lf = fminf(fmaxf(lf, 0.0f), 0.26f);
    }
    double t31 = 3.0 * e1, t22 = 2.0 * e2;
    double lam = (double)lf;
#pragma unroll
    for (int itn = 0; itn < 4; ++itn) {
        double p  = (((lam - e1) * lam + e2) * lam - e3) * lam + e4;
        double dp = ((4.0 * lam - t31) * lam + t22) * lam - e3;
        dp = fmin(dp, -1e-30);
        lam = lam - p * crcp(dp);  // 1e-5-accurate step: self-correcting
        lam = fmin(fmax(lam, 0.0), 0.26);
    }

    // ---- Adjugate of B = M - lam I via shared Laplace 2x2 minors (f64) ----
    double d0 = m00 - lam, d1 = m11 - lam, d2 = m22 - lam, d3 = m33 - lam;
    double s0 = d0 * d1 - m01 * m01;
    double s1 = d0 * m12 - m01 * m02;
    double s2 = d0 * m13 - m01 * m03;
    double s3 = m01 * m12 - d1 * m02;
    double s4 = m01 * m13 - d1 * m03;
    double s5 = m02 * m13 - m12 * m03;   // = c0 by symmetry
    double c1 = m02 * m23 - m03 * d2;
    double c2 = m02 * d3 - m03 * m23;
    double c3 = m12 * m23 - m13 * d2;
    double c4 = m12 * d3 - m13 * m23;
    double c5 = d2 * d3 - m23 * m23;

    // ---- Convert entries once; selection + normalization in f32 ----
    float f00 = (float)( d1 * c5 - m12 * c4 + m13 * c3);
    float f01 = (float)(-m01 * c5 + m02 * c4 - m03 * c3);
    float f02 = (float)( m13 * s5 - m23 * s4 + d3 * s3);
    float f03 = (float)(-m12 * s5 + d2 * s4 - m23 * s3);
    float f11 = (float)( d0 * c5 - m02 * c2 + m03 * c1);
    float f12 = (float)(-m03 * s5 + m23 * s2 - d3 * s1);
    float f13 = (float)( m02 * s5 - d2 * s2 + m23 * s1);
    float f22 = (float)( m03 * s4 - m13 * s2 + d3 * s0);
    float f23 = (float)(-m02 * s4 + m12 * s2 - m23 * s0);
    float f33 = (float)( m02 * s3 - m12 * s1 + d2 * s0);

    // pick column with largest |diagonal| (= largest v1 comp^2; adj = c*v v^T)
    float bb = fabsf(f00);
    float fx = f00, fy = f01, fz = f02;
    float a1 = fabsf(f11);
    if (a1 > bb) { bb = a1; fx = f01; fy = f11; fz = f12; }
    float a2 = fabsf(f22);
    if (a2 > bb) { bb = a2; fx = f02; fy = f12; fz = f22; }
    float a3 = fabsf(f33);
    if (a3 > bb) { bb = a3; fx = f03; fy = f13; fz = f23; }

    float nd = fx * fx + fy * fy + fz * fz;
    float inv = __builtin_amdgcn_rsqf(fmaxf(nd, 1e-30f));
    float nx = fx * inv, ny = fy * inv, nz = fz * inv;

    int o = y * WW + x;
    float cx = px[4], cy = py[4], cz = pz[4];
    float dot = nx * cx + ny * cy + nz * cz;
    float sgn = (dot > 0.0f) ? 1.0f : ((dot < 0.0f) ? -1.0f : 0.0f);
    nx *= sgn; ny *= sgn; nz *= sgn;

    out[((size_t)b * 3 + 0) * HW + o] = nx;
    out[((size_t)b * 3 + 1) * HW + o] = ny;
    out[((size_t)b * 3 + 2) * HW + o] = nz;

    bool cvalid = (cz > 0.0f && cz < 10.0f);
    bool m = cvalid && (cnt >= 4.0f) && (nx * nx + ny * ny + nz * nz > 0.25f);
    out[(size_t)BB * 3 * HW + (size_t)b * HW + o] = m ? 1.0f : 0.0f;
}

extern "C" void kernel_launch(void* const* d_in, const int* in_sizes, int n_in,
                              void* d_out, int out_size, void* d_ws, size_t ws_size,
                              hipStream_t stream) {
    const float* pts = (const float*)d_in[0];
    float* out = (float*)d_out;
    int total = BB * HH * WW;
    d2n_kernel<<<(total + 255) / 256, 256, 0, stream>>>(pts, out);
}